// Round 6
// baseline (2672.622 us; speedup 1.0000x reference)
//
#include <hip/hip_runtime.h>
#include <cmath>

static constexpr float SCALE_ = 0.17677669529663687f; // 32^-0.5

typedef __attribute__((ext_vector_type(8))) short bf16x8;
typedef __attribute__((ext_vector_type(8))) ushort u16x8;
typedef __attribute__((ext_vector_type(4))) float f32x4;

__device__ inline ushort bf16h(float f) {
    uint x = __float_as_uint(f);
    return (ushort)((x + 0x7fffu + ((x >> 16) & 1u)) >> 16);
}
__device__ inline float bf16f(ushort u) {
    return __uint_as_float(((uint)u) << 16);
}

// ---------------------------------------------------------------------------
// Small weight-combine GEMM (f32): out[m,n] = scale * sum_k Wa[m,k]*Wb[k,n]
// ---------------------------------------------------------------------------
__global__ __launch_bounds__(256) void smallmm_kernel(
    const float* __restrict__ Wa, const float* __restrict__ Wb,
    const float* __restrict__ scale_p, float* __restrict__ out, int NCb)
{
    int idx = blockIdx.x * 256 + threadIdx.x;
    int n4  = NCb >> 2;
    int m   = idx / n4;
    int n0  = (idx - m * n4) << 2;
    if (m >= 192) return;
    float s = scale_p[0];
    float ax = 0.f, ay = 0.f, az = 0.f, aw = 0.f;
    for (int k = 0; k < 192; ++k) {
        float a = Wa[m * 192 + k];
        const float4 b = *(const float4*)(Wb + (size_t)k * NCb + n0);
        ax += a * b.x; ay += a * b.y; az += a * b.z; aw += a * b.w;
    }
    float4 r = make_float4(ax * s, ay * s, az * s, aw * s);
    *(float4*)(out + (size_t)m * NCb + n0) = r;
}

// ---------------------------------------------------------------------------
// Activation f32 -> K-slabbed bf16 hi/lo [6][Mc][32]
// ---------------------------------------------------------------------------
__global__ __launch_bounds__(256) void conv_x(
    const float* __restrict__ src, long long src_bs,
    ushort* __restrict__ dh, ushort* __restrict__ dl, int Mc)
{
    const long long SS = (long long)Mc * 32;
    const long long total8 = (long long)Mc * 24;
    for (long long t = (long long)blockIdx.x * 256 + threadIdx.x; t < total8;
         t += (long long)gridDim.x * 256) {
        int m  = (int)(t / 24);
        int c8 = (int)(t - (long long)m * 24) * 8;
        int bb = m / 49, r = m - bb * 49;
        const float* sp = src + (long long)bb * src_bs + r * 192 + c8;
        float4 v0 = *(const float4*)sp;
        float4 v1 = *(const float4*)(sp + 4);
        float f[8] = {v0.x, v0.y, v0.z, v0.w, v1.x, v1.y, v1.z, v1.w};
        u16x8 h8, l8;
        #pragma unroll
        for (int e = 0; e < 8; ++e) {
            ushort hh = bf16h(f[e]);
            h8[e] = hh;
            l8[e] = bf16h(f[e] - bf16f(hh));
        }
        long long o = (long long)(c8 >> 5) * SS + (long long)m * 32 + (c8 & 31);
        *(u16x8*)(dh + o) = h8;
        *(u16x8*)(dl + o) = l8;
    }
}

// ---------------------------------------------------------------------------
// Weight f32 [192][NC] -> K-slabbed transposed bf16 hi/lo [6][NC][32]
// ---------------------------------------------------------------------------
__global__ __launch_bounds__(256) void conv_wT(
    const float* __restrict__ W, int NC,
    ushort* __restrict__ dh, ushort* __restrict__ dl)
{
    int idx = blockIdx.x * 256 + threadIdx.x;
    if (idx >= NC * 192) return;
    int n = idx / 192, k = idx - n * 192;
    float f = W[(long long)k * NC + n];
    long long o = ((long long)(k >> 5) * NC + n) * 32 + (k & 31);
    ushort hh = bf16h(f);
    dh[o] = hh;
    dl[o] = bf16h(f - bf16f(hh));
}

// ---------------------------------------------------------------------------
// LDS-free, barrier-free split-bf16 MFMA GEMM on K-slabbed planes.
// A: [6][M][32] hi/lo per operand; W: [6][NC][32] hi/lo. Fragments are
// contiguous 16B loads (wave covers 16 rows x 64B = 1KB coalesced).
// Block 128M x 96N, 4 waves (2m x 2n), wave 64x48. XCD-bijective swizzle.
// OUTMODE 0: slabbed hi/lo out; cols >= vcol0 go TRANSPOSED per (head,batch)
//            to vT [6][NB][32][64] hi/lo (attn PV fragment layout).
// OUTMODE 1: f32 scatter (b2=m/49, row stride 192 at out_bs batch stride).
// ---------------------------------------------------------------------------
template<int NC, bool DUAL, int OUTMODE>
__global__ __launch_bounds__(256, 3) void gemm_ds(
    const ushort* __restrict__ Ah1, const ushort* __restrict__ Al1,
    const ushort* __restrict__ Ah2, const ushort* __restrict__ Al2,
    const ushort* __restrict__ Bh1, const ushort* __restrict__ Bl1,
    const ushort* __restrict__ Bh2, const ushort* __restrict__ Bl2,
    const float* __restrict__ bias,
    ushort* __restrict__ outH, ushort* __restrict__ outL,
    int vcol0, ushort* __restrict__ vTh, ushort* __restrict__ vTl, int NB,
    float* __restrict__ outF, long long out_bs,
    int M)
{
    constexpr int GX = NC / 96;
    // bijective XCD swizzle: XCD x gets a contiguous id range
    const int nwg = gridDim.x;
    {
    }
    int orig = blockIdx.x;
    int q8 = nwg >> 3, r8 = nwg & 7;
    int xc = orig & 7, ix = orig >> 3;
    int id = (xc < r8 ? xc * (q8 + 1) : r8 * (q8 + 1) + (xc - r8) * q8) + ix;
    const int bm = id / GX, bn = id - bm * GX;

    const int tid = threadIdx.x;
    const int lane = tid & 63, wv = tid >> 6;
    const int wm = (wv >> 1) * 64, wn = (wv & 1) * 48;
    const int lr = lane & 15, lg = lane >> 4;
    const long long SS = (long long)M * 32;

    int row0 = bm * 128 + wm + lr;
    int rclamp = (row0 + 48 >= M) ? 1 : 0;   // any clamping needed?
    int aoff_i[4];
    #pragma unroll
    for (int i = 0; i < 4; ++i) {
        int m = row0 + 16 * i;
        if (rclamp && m >= M) m = M - 1;
        aoff_i[i] = m * 32 + 8 * lg;
    }
    const int boff0 = (bn * 96 + wn + lr) * 32 + 8 * lg;

    f32x4 acc[4][3] = {};
    constexpr int NS = DUAL ? 12 : 6;

    #pragma unroll
    for (int s = 0; s < NS; ++s) {
        const int k6 = (s < 6) ? s : s - 6;
        const ushort* AH = (!DUAL || s < 6) ? Ah1 : Ah2;
        const ushort* AL = (!DUAL || s < 6) ? Al1 : Al2;
        const ushort* BH = (!DUAL || s < 6) ? Bh1 : Bh2;
        const ushort* BL = (!DUAL || s < 6) ? Bl1 : Bl2;
        const long long asb = (long long)k6 * SS;
        const int bsb = k6 * (NC * 32);

        bf16x8 ah[4], al[4], bh[3], bl[3];
        #pragma unroll
        for (int i = 0; i < 4; ++i) {
            ah[i] = *(const bf16x8*)(AH + asb + aoff_i[i]);
            al[i] = *(const bf16x8*)(AL + asb + aoff_i[i]);
        }
        #pragma unroll
        for (int j = 0; j < 3; ++j) {
            bh[j] = *(const bf16x8*)(BH + bsb + boff0 + j * 512);
            bl[j] = *(const bf16x8*)(BL + bsb + boff0 + j * 512);
        }
        #pragma unroll
        for (int i = 0; i < 4; ++i)
            #pragma unroll
            for (int j = 0; j < 3; ++j) {
                acc[i][j] = __builtin_amdgcn_mfma_f32_16x16x32_bf16(ah[i], bh[j], acc[i][j], 0, 0, 0);
                acc[i][j] = __builtin_amdgcn_mfma_f32_16x16x32_bf16(ah[i], bl[j], acc[i][j], 0, 0, 0);
                acc[i][j] = __builtin_amdgcn_mfma_f32_16x16x32_bf16(al[i], bh[j], acc[i][j], 0, 0, 0);
            }
    }

    #pragma unroll
    for (int j = 0; j < 3; ++j) {
        const int c = bn * 96 + wn + 16 * j + lr;
        const float bv = bias ? bias[c] : 0.f;
        #pragma unroll
        for (int i = 0; i < 4; ++i)
            #pragma unroll
            for (int r = 0; r < 4; ++r) {
                int m = bm * 128 + wm + 16 * i + 4 * lg + r;
                if (m < M) {
                    float f = acc[i][j][r] + bv;
                    if constexpr (OUTMODE == 1) {
                        int b2 = m / 49, r2 = m - b2 * 49;
                        outF[(long long)b2 * out_bs + r2 * 192 + c] = f;
                    } else {
                        ushort hh = bf16h(f);
                        ushort ll = bf16h(f - bf16f(hh));
                        if (c >= vcol0) {
                            int vc = c - vcol0;
                            int h = vc >> 5, dd = vc & 31;
                            int b2 = m / 49, jj = m - b2 * 49;
                            long long o = (((long long)h * NB + b2) << 11) + dd * 64 + jj;
                            vTh[o] = hh;
                            vTl[o] = ll;
                        } else {
                            long long o = (long long)(c >> 5) * SS + (long long)m * 32 + (c & 31);
                            outH[o] = hh;
                            outL[o] = ll;
                        }
                    }
                }
            }
    }
}

// ---------------------------------------------------------------------------
// MFMA differential attention; q/k slabbed [6][M][32] hi/lo, V as transposed
// per-(head,batch) tiles [32][64] hi/lo. One (batch,head)/block, 4 waves,
// swapped QK^T -> lane-local softmax, wave-private P LDS, no inter-wave sync.
// ---------------------------------------------------------------------------
__global__ __launch_bounds__(256, 4) void attn_bf(
    const ushort* __restrict__ qTh, const ushort* __restrict__ qTl,
    const ushort* __restrict__ kTh, const ushort* __restrict__ kTl,
    const ushort* __restrict__ vTth, const ushort* __restrict__ vTtl,
    const ushort* __restrict__ qRh, const ushort* __restrict__ qRl,
    const ushort* __restrict__ kRh, const ushort* __restrict__ kRl,
    const ushort* __restrict__ vTrh, const ushort* __restrict__ vTrl,
    long long SS, int NB,
    const float* __restrict__ rpb, const float* __restrict__ lam_ptr,
    ushort* __restrict__ otH, ushort* __restrict__ otL,
    ushort* __restrict__ orH, ushort* __restrict__ orL)
{
    __shared__ __align__(16) ushort Pth[64][72];
    __shared__ __align__(16) ushort Ptl[64][72];
    __shared__ float bias_s[169];

    const int tid = threadIdx.x;
    const int bb = blockIdx.x / 6;
    const int h  = blockIdx.x - bb * 6;
    const int lane = tid & 63;
    const int w  = tid >> 6;
    const int li = lane & 15;
    const int lg = lane >> 4;
    const long long rowbase = (long long)bb * 49 * 32;
    const long long hb = (long long)h * SS + rowbase;

    for (int idx = tid; idx < 169; idx += 256) bias_s[idx] = rpb[idx * 6 + h];

    float lraw = lam_ptr[0];
    float lam = 1.f / (1.f + __expf(-lraw));
    lam = fminf(fmaxf(lam, 0.01f), 0.99f);

    const int irow = min(w * 16 + li, 48);

    // ---- scores via swapped MFMA ----
    f32x4 st[2][4];
    #pragma unroll
    for (int s = 0; s < 2; ++s) {
        const ushort* qhb = (s ? qRh : qTh) + hb;
        const ushort* qlb = (s ? qRl : qTl) + hb;
        const ushort* khb = (s ? kRh : kTh) + hb;
        const ushort* klb = (s ? kRl : kTl) + hb;

        bf16x8 qh = *(const bf16x8*)(qhb + irow * 32 + 8 * lg);
        bf16x8 ql = *(const bf16x8*)(qlb + irow * 32 + 8 * lg);
        #pragma unroll
        for (int jt = 0; jt < 4; ++jt) {
            int jr = jt * 16 + li; if (jr > 48) jr = 48;
            bf16x8 kh = *(const bf16x8*)(khb + jr * 32 + 8 * lg);
            bf16x8 kl = *(const bf16x8*)(klb + jr * 32 + 8 * lg);
            f32x4 c = {};
            c = __builtin_amdgcn_mfma_f32_16x16x32_bf16(kh, qh, c, 0, 0, 0);
            c = __builtin_amdgcn_mfma_f32_16x16x32_bf16(kh, ql, c, 0, 0, 0);
            c = __builtin_amdgcn_mfma_f32_16x16x32_bf16(kl, qh, c, 0, 0, 0);
            st[s][jt] = c;
        }
    }
    __syncthreads();   // bias_s ready (only barrier)

    // ---- bias + mask + softmax (row i = w*16+li lane-local) ----
    const int ri = (irow * 9363) >> 16;
    const int ci = irow - 7 * ri;
    float bias_v[4][4];
    #pragma unroll
    for (int jt = 0; jt < 4; ++jt)
        #pragma unroll
        for (int r = 0; r < 4; ++r) {
            int j = jt * 16 + 4 * lg + r;
            int jc = (j < 49) ? j : 48;
            int rj = (jc * 9363) >> 16;
            int cj = jc - 7 * rj;
            bias_v[jt][r] = bias_s[(ri - rj + 6) * 13 + (ci - cj + 6)];
        }

    float p[2][4][4];
    #pragma unroll
    for (int s = 0; s < 2; ++s) {
        float m = -1e30f;
        #pragma unroll
        for (int jt = 0; jt < 4; ++jt)
            #pragma unroll
            for (int r = 0; r < 4; ++r) {
                int j = jt * 16 + 4 * lg + r;
                float sv = (j < 49) ? (st[s][jt][r] * SCALE_ + bias_v[jt][r]) : -1e30f;
                p[s][jt][r] = sv;
                m = fmaxf(m, sv);
            }
        m = fmaxf(m, __shfl_xor(m, 16));
        m = fmaxf(m, __shfl_xor(m, 32));
        float sum = 0.f;
        #pragma unroll
        for (int jt = 0; jt < 4; ++jt)
            #pragma unroll
            for (int r = 0; r < 4; ++r) {
                float e = __expf(p[s][jt][r] - m);
                p[s][jt][r] = e;
                sum += e;
            }
        sum += __shfl_xor(sum, 16);
        sum += __shfl_xor(sum, 32);
        float inv = 1.f / sum;
        #pragma unroll
        for (int jt = 0; jt < 4; ++jt)
            #pragma unroll
            for (int r = 0; r < 4; ++r)
                p[s][jt][r] *= inv;
    }

    // ---- PV: Peff via wave-private LDS; V from transposed tiles ----
    const int prow = w * 16 + li;
    #pragma unroll
    for (int s = 0; s < 2; ++s) {
        #pragma unroll
        for (int jt = 0; jt < 4; ++jt) {
            ushort4 h4, l4;
            #pragma unroll
            for (int r = 0; r < 4; ++r) {
                float at = p[0][jt][r], ar = p[1][jt][r];
                float f = (s == 0) ? (at - lam * ar) : (ar - lam * at);
                ushort hh = bf16h(f);
                ((ushort*)&h4)[r] = hh;
                ((ushort*)&l4)[r] = bf16h(f - bf16f(hh));
            }
            *(ushort4*)&Pth[prow][jt * 16 + 4 * lg] = h4;
            *(ushort4*)&Ptl[prow][jt * 16 + 4 * lg] = l4;
        }

        const ushort* vth = (s ? vTrh : vTth) + (((long long)h * NB + bb) << 11);
        const ushort* vtl = (s ? vTrl : vTtl) + (((long long)h * NB + bb) << 11);
        f32x4 acc[2] = {};
        #pragma unroll
        for (int ks = 0; ks < 2; ++ks) {
            bf16x8 pah = *(const bf16x8*)&Pth[prow][ks * 32 + 8 * lg];
            bf16x8 pal = *(const bf16x8*)&Ptl[prow][ks * 32 + 8 * lg];
            #pragma unroll
            for (int dt = 0; dt < 2; ++dt) {
                bf16x8 vh = *(const bf16x8*)(vth + (dt * 16 + li) * 64 + ks * 32 + 8 * lg);
                bf16x8 vl = *(const bf16x8*)(vtl + (dt * 16 + li) * 64 + ks * 32 + 8 * lg);
                acc[dt] = __builtin_amdgcn_mfma_f32_16x16x32_bf16(pah, vh, acc[dt], 0, 0, 0);
                acc[dt] = __builtin_amdgcn_mfma_f32_16x16x32_bf16(pah, vl, acc[dt], 0, 0, 0);
                acc[dt] = __builtin_amdgcn_mfma_f32_16x16x32_bf16(pal, vh, acc[dt], 0, 0, 0);
            }
        }
        ushort* oph = s ? orH : otH;
        ushort* opl = s ? orL : otL;
        #pragma unroll
        for (int dt = 0; dt < 2; ++dt)
            #pragma unroll
            for (int r = 0; r < 4; ++r) {
                int i = w * 16 + 4 * lg + r;
                if (i < 49) {
                    long long o = (long long)h * SS + rowbase + (long long)i * 32 + dt * 16 + li;
                    float f = acc[dt][r];
                    ushort hh = bf16h(f);
                    oph[o] = hh;
                    opl[o] = bf16h(f - bf16f(hh));
                }
            }
    }
}

// ---------------------------------------------------------------------------
extern "C" void kernel_launch(void* const* d_in, const int* in_sizes, int n_in,
                              void* d_out, int out_size, void* d_ws, size_t ws_size,
                              hipStream_t stream)
{
    const float* x_sa      = (const float*)d_in[0];
    const float* x_ca      = (const float*)d_in[1];
    const float* lam_sa    = (const float*)d_in[2];
    const float* lam_ca    = (const float*)d_in[3];
    const float* sa_enh    = (const float*)d_in[4];
    const float* ca_enh    = (const float*)d_in[5];
    const float* W_sa_qkv  = (const float*)d_in[6];
    const float* b_sa_qkv  = (const float*)d_in[7];
    const float* W_sa_ct   = (const float*)d_in[8];
    const float* W_sa_cr   = (const float*)d_in[9];
    const float* W_ca_q    = (const float*)d_in[10];
    const float* b_ca_q    = (const float*)d_in[11];
    const float* W_ca_kv   = (const float*)d_in[12];
    const float* b_ca_kv   = (const float*)d_in[13];
    const float* W_ca_ct   = (const float*)d_in[14];
    const float* W_ca_cr   = (const float*)d_in[15];
    const float* rpb       = (const float*)d_in[16];
    const float* W_proj_sa = (const float*)d_in[17];
    const float* b_proj_sa = (const float*)d_in[18];
    const float* W_proj_ca = (const float*)d_in[19];
    const float* b_proj_ca = (const float*)d_in[20];
    float* out = (float*)d_out;
    float* ws  = (float*)d_ws;

    // ---- f32 combined-weight temps ----
    float* CW0 = ws;             // 192x576
    float* CW1 = CW0 + 110592;
    float* CW2 = CW1 + 110592;   // 192x192
    float* CW3 = CW2 + 36864;
    float* CW4 = CW3 + 36864;    // 192x384
    float* CW5 = CW4 + 73728;

    smallmm_kernel<<<108, 256, 0, stream>>>(W_sa_cr, W_sa_qkv, sa_enh, CW0, 576);
    smallmm_kernel<<<108, 256, 0, stream>>>(W_sa_ct, W_sa_qkv, sa_enh, CW1, 576);
    smallmm_kernel<<< 36, 256, 0, stream>>>(W_ca_cr, W_ca_q,   ca_enh, CW2, 192);
    smallmm_kernel<<< 36, 256, 0, stream>>>(W_ca_ct, W_ca_q,   ca_enh, CW3, 192);
    smallmm_kernel<<< 72, 256, 0, stream>>>(W_ca_cr, W_ca_kv,  ca_enh, CW4, 384);
    smallmm_kernel<<< 72, 256, 0, stream>>>(W_ca_ct, W_ca_kv,  ca_enh, CW5, 384);

    // ---- K-slabbed bf16 hi/lo weights ----
    ushort* wb = (ushort*)(ws + 442368);
    ushort* WsaqH = wb;                  ushort* WsaqL = WsaqH + 110592;
    ushort* C0H  = WsaqL + 110592;       ushort* C0L  = C0H + 110592;
    ushort* C1H  = C0L + 110592;         ushort* C1L  = C1H + 110592;
    ushort* WcqH = C1L + 110592;         ushort* WcqL = WcqH + 36864;
    ushort* C2H  = WcqL + 36864;         ushort* C2L  = C2H + 36864;
    ushort* C3H  = C2L + 36864;          ushort* C3L  = C3H + 36864;
    ushort* WckH = C3L + 36864;          ushort* WckL = WckH + 73728;
    ushort* C4H  = WckL + 73728;         ushort* C4L  = C4H + 73728;
    ushort* C5H  = C4L + 73728;          ushort* C5L  = C5H + 73728;
    ushort* WpsH = C5L + 73728;          ushort* WpsL = WpsH + 36864;
    ushort* WpcH = WpsL + 36864;         ushort* WpcL = WpcH + 36864;
    ushort* chunkU = WpcL + 36864;       // = wb + 1474560

    conv_wT<<<432, 256, 0, stream>>>(W_sa_qkv, 576, WsaqH, WsaqL);
    conv_wT<<<432, 256, 0, stream>>>(CW0,      576, C0H,  C0L);
    conv_wT<<<432, 256, 0, stream>>>(CW1,      576, C1H,  C1L);
    conv_wT<<<144, 256, 0, stream>>>(W_ca_q,   192, WcqH, WcqL);
    conv_wT<<<144, 256, 0, stream>>>(CW2,      192, C2H,  C2L);
    conv_wT<<<144, 256, 0, stream>>>(CW3,      192, C3H,  C3L);
    conv_wT<<<288, 256, 0, stream>>>(W_ca_kv,  384, WckH, WckL);
    conv_wT<<<288, 256, 0, stream>>>(CW4,      384, C4H,  C4L);
    conv_wT<<<288, 256, 0, stream>>>(CW5,      384, C5H,  C5L);
    conv_wT<<<144, 256, 0, stream>>>(W_proj_sa,192, WpsH, WpsL);
    conv_wT<<<144, 256, 0, stream>>>(W_proj_ca,192, WpcH, WpcL);

    // ---- chunking: 399360 bytes per batch element ----
    long long avail = (long long)ws_size - 442368LL * 4 - 1474560LL * 2;
    int cbmax = (int)(avail / 399360);
    if (cbmax > 2048) cbmax = 2048;
    if (cbmax < 1) cbmax = 1;

    const long long OUT1 = 2LL * 2048 * 49 * 192;
    dim3 blk(256);
    const int BIGC = 1 << 30;

    for (int c0 = 0; c0 < 2048; c0 += cbmax) {
        int cb = (c0 + cbmax <= 2048) ? cbmax : (2048 - c0);
        int M = cb * 49;
        long long SS = (long long)M * 32;
        int gy = (M + 127) / 128;
        int cblk = (int)(((long long)M * 24 + 255) / 256);
        if (cblk > 4096) cblk = 4096;

        dim3 g6(6 * gy), g4(4 * gy), g2(2 * gy);

        // =========================== SA branch ===========================
        ushort* XtH = chunkU;                              // [6][M][32] each
        ushort* XtL = XtH + (long long)cbmax * 9408;
        ushort* XrH = XtL + (long long)cbmax * 9408;
        ushort* XrL = XrH + (long long)cbmax * 9408;
        ushort* QtH = XrL + (long long)cbmax * 9408;       // q,k: [12][M][32]
        ushort* QtL = QtH + (long long)cbmax * 18816;
        ushort* QrH = QtL + (long long)cbmax * 18816;
        ushort* QrL = QrH + (long long)cbmax * 18816;
        ushort* VtTH = QrL + (long long)cbmax * 18816;     // vT: [6][NB][32][64]
        ushort* VtTL = VtTH + (long long)cbmax * 12288;
        ushort* VrTH = VtTL + (long long)cbmax * 12288;
        ushort* VrTL = VrTH + (long long)cbmax * 12288;
        ushort* OtH = VrTL + (long long)cbmax * 12288;     // [6][M][32]
        ushort* OtL = OtH + (long long)cbmax * 9408;
        ushort* OrH = OtL + (long long)cbmax * 9408;
        ushort* OrL = OrH + (long long)cbmax * 9408;

        conv_x<<<cblk, blk, 0, stream>>>(x_sa + (long long)c0 * 9408, 9408, XtH, XtL, M);
        conv_x<<<cblk, blk, 0, stream>>>(x_sa + (2048LL + c0) * 9408, 9408, XrH, XrL, M);

        gemm_ds<576, true, 0><<<g6, blk, 0, stream>>>(
            XtH, XtL, XrH, XrL, WsaqH, WsaqL, C0H, C0L,
            b_sa_qkv, QtH, QtL, 384, VtTH, VtTL, cb, nullptr, 0, M);
        gemm_ds<576, true, 0><<<g6, blk, 0, stream>>>(
            XrH, XrL, XtH, XtL, WsaqH, WsaqL, C1H, C1L,
            b_sa_qkv, QrH, QrL, 384, VrTH, VrTL, cb, nullptr, 0, M);

        attn_bf<<<cb * 6, blk, 0, stream>>>(
            QtH,          QtL,
            QtH + 6 * SS, QtL + 6 * SS,
            VtTH,         VtTL,
            QrH,          QrL,
            QrH + 6 * SS, QrL + 6 * SS,
            VrTH,         VrTL,
            SS, cb, rpb, lam_sa, OtH, OtL, OrH, OrL);

        gemm_ds<192, false, 1><<<g2, blk, 0, stream>>>(
            OtH, OtL, nullptr, nullptr, WpsH, WpsL, nullptr, nullptr,
            b_proj_sa, nullptr, nullptr, BIGC, nullptr, nullptr, cb,
            out + (long long)c0 * 9408, 9408, M);
        gemm_ds<192, false, 1><<<g2, blk, 0, stream>>>(
            OrH, OrL, nullptr, nullptr, WpsH, WpsL, nullptr, nullptr,
            b_proj_sa, nullptr, nullptr, BIGC, nullptr, nullptr, cb,
            out + (2048LL + c0) * 9408, 9408, M);

        // =========================== CA branch ===========================
        ushort* CXtH = chunkU;                             // [6][M][32]
        ushort* CXtL = CXtH + (long long)cbmax * 9408;
        ushort* CXrH = CXtL + (long long)cbmax * 9408;
        ushort* CXrL = CXrH + (long long)cbmax * 9408;
        ushort* CQtH = CXrL + (long long)cbmax * 9408;     // [6][M][32]
        ushort* CQtL = CQtH + (long long)cbmax * 9408;
        ushort* CQrH = CQtL + (long long)cbmax * 9408;
        ushort* CQrL = CQrH + (long long)cbmax * 9408;
        ushort* KtH  = CQrL + (long long)cbmax * 9408;     // k: [6][M][32]
        ushort* KtL  = KtH + (long long)cbmax * 9408;
        ushort* KrH  = KtL + (long long)cbmax * 9408;
        ushort* KrL  = KrH + (long long)cbmax * 9408;
        ushort* CVtTH = KrL + (long long)cbmax * 9408;     // vT tiles
        ushort* CVtTL = CVtTH + (long long)cbmax * 12288;
        ushort* CVrTH = CVtTL + (long long)cbmax * 12288;
        ushort* CVrTL = CVrTH + (long long)cbmax * 12288;
        ushort* COtH = CVrTL + (long long)cbmax * 12288;   // [6][M][32]
        ushort* COtL = COtH + (long long)cbmax * 9408;
        ushort* COrH = COtL + (long long)cbmax * 9408;
        ushort* COrL = COrH + (long long)cbmax * 9408;

        conv_x<<<cblk, blk, 0, stream>>>(x_ca + (long long)c0 * 18816, 18816, CXtH, CXtL, M);
        conv_x<<<cblk, blk, 0, stream>>>(x_ca + (long long)c0 * 18816 + 9408, 18816, CXrH, CXrL, M);

        gemm_ds<192, true, 0><<<g2, blk, 0, stream>>>(
            CXtH, CXtL, CXrH, CXrL, WcqH, WcqL, C2H, C2L,
            b_ca_q, CQtH, CQtL, BIGC, nullptr, nullptr, cb, nullptr, 0, M);
        gemm_ds<192, true, 0><<<g2, blk, 0, stream>>>(
            CXrH, CXrL, CXtH, CXtL, WcqH, WcqL, C3H, C3L,
            b_ca_q, CQrH, CQrL, BIGC, nullptr, nullptr, cb, nullptr, 0, M);

        gemm_ds<384, true, 0><<<g4, blk, 0, stream>>>(
            CXtH, CXtL, CXrH, CXrL, WckH, WckL, C4H, C4L,
            b_ca_kv, KtH, KtL, 192, CVtTH, CVtTL, cb, nullptr, 0, M);
        gemm_ds<384, true, 0><<<g4, blk, 0, stream>>>(
            CXrH, CXrL, CXtH, CXtL, WckH, WckL, C5H, C5L,
            b_ca_kv, KrH, KrL, 192, CVrTH, CVrTL, cb, nullptr, 0, M);

        attn_bf<<<cb * 6, blk, 0, stream>>>(
            CQtH,  CQtL,
            KtH,   KtL,
            CVtTH, CVtTL,
            CQrH,  CQrL,
            KrH,   KrL,
            CVrTH, CVrTL,
            SS, cb, rpb, lam_ca, COtH, COtL, COrH, COrL);

        gemm_ds<192, false, 1><<<g2, blk, 0, stream>>>(
            COtH, COtL, nullptr, nullptr, WpcH, WpcL, nullptr, nullptr,
            b_proj_ca, nullptr, nullptr, BIGC, nullptr, nullptr, cb,
            out + OUT1 + (long long)c0 * 18816, 18816, M);
        gemm_ds<192, false, 1><<<g2, blk, 0, stream>>>(
            COrH, COrL, nullptr, nullptr, WpcH, WpcL, nullptr, nullptr,
            b_proj_ca, nullptr, nullptr, BIGC, nullptr, nullptr, cb,
            out + OUT1 + (long long)c0 * 18816 + 9408, 18816, M);
    }
}

// Round 7
// 1654.903 us; speedup vs baseline: 1.6150x; 1.6150x over previous
//
#include <hip/hip_runtime.h>
#include <cmath>

static constexpr float SCALE_ = 0.17677669529663687f; // 32^-0.5

typedef __attribute__((ext_vector_type(8))) short bf16x8;
typedef __attribute__((ext_vector_type(8))) ushort u16x8;
typedef __attribute__((ext_vector_type(4))) float f32x4;

__device__ inline ushort bf16h(float f) {
    uint x = __float_as_uint(f);
    return (ushort)((x + 0x7fffu + ((x >> 16) & 1u)) >> 16);
}
__device__ inline float bf16f(ushort u) {
    return __uint_as_float(((uint)u) << 16);
}

// async global->LDS, 16B per lane; LDS dest = wave-uniform base + lane*16
__device__ __forceinline__ void gld16(const ushort* g, ushort* l) {
    __builtin_amdgcn_global_load_lds(
        (const __attribute__((address_space(1))) unsigned int*)g,
        (__attribute__((address_space(3))) unsigned int*)l,
        16, 0, 0);
}

// ---------------------------------------------------------------------------
// Small weight-combine GEMM (f32): out[m,n] = scale * sum_k Wa[m,k]*Wb[k,n]
// ---------------------------------------------------------------------------
__global__ __launch_bounds__(256) void smallmm_kernel(
    const float* __restrict__ Wa, const float* __restrict__ Wb,
    const float* __restrict__ scale_p, float* __restrict__ out, int NCb)
{
    int idx = blockIdx.x * 256 + threadIdx.x;
    int n4  = NCb >> 2;
    int m   = idx / n4;
    int n0  = (idx - m * n4) << 2;
    if (m >= 192) return;
    float s = scale_p[0];
    float ax = 0.f, ay = 0.f, az = 0.f, aw = 0.f;
    for (int k = 0; k < 192; ++k) {
        float a = Wa[m * 192 + k];
        const float4 b = *(const float4*)(Wb + (size_t)k * NCb + n0);
        ax += a * b.x; ay += a * b.y; az += a * b.z; aw += a * b.w;
    }
    float4 r = make_float4(ax * s, ay * s, az * s, aw * s);
    *(float4*)(out + (size_t)m * NCb + n0) = r;
}

// ---------------------------------------------------------------------------
// Activation f32 -> K-slabbed bf16 hi/lo [6][Mc][32]
// ---------------------------------------------------------------------------
__global__ __launch_bounds__(256) void conv_x(
    const float* __restrict__ src, long long src_bs,
    ushort* __restrict__ dh, ushort* __restrict__ dl, int Mc)
{
    const long long SS = (long long)Mc * 32;
    const long long total8 = (long long)Mc * 24;
    for (long long t = (long long)blockIdx.x * 256 + threadIdx.x; t < total8;
         t += (long long)gridDim.x * 256) {
        int m  = (int)(t / 24);
        int c8 = (int)(t - (long long)m * 24) * 8;
        int bb = m / 49, r = m - bb * 49;
        const float* sp = src + (long long)bb * src_bs + r * 192 + c8;
        float4 v0 = *(const float4*)sp;
        float4 v1 = *(const float4*)(sp + 4);
        float f[8] = {v0.x, v0.y, v0.z, v0.w, v1.x, v1.y, v1.z, v1.w};
        u16x8 h8, l8;
        #pragma unroll
        for (int e = 0; e < 8; ++e) {
            ushort hh = bf16h(f[e]);
            h8[e] = hh;
            l8[e] = bf16h(f[e] - bf16f(hh));
        }
        long long o = (long long)(c8 >> 5) * SS + (long long)m * 32 + (c8 & 31);
        *(u16x8*)(dh + o) = h8;
        *(u16x8*)(dl + o) = l8;
    }
}

// ---------------------------------------------------------------------------
// Weight f32 [192][NC] -> K-slabbed transposed bf16 hi/lo [6][NC][32]
// ---------------------------------------------------------------------------
__global__ __launch_bounds__(256) void conv_wT(
    const float* __restrict__ W, int NC,
    ushort* __restrict__ dh, ushort* __restrict__ dl)
{
    int idx = blockIdx.x * 256 + threadIdx.x;
    if (idx >= NC * 192) return;
    int n = idx / 192, k = idx - n * 192;
    float f = W[(long long)k * NC + n];
    long long o = ((long long)(k >> 5) * NC + n) * 32 + (k & 31);
    ushort hh = bf16h(f);
    dh[o] = hh;
    dl[o] = bf16h(f - bf16f(hh));
}

// ---------------------------------------------------------------------------
// m97-structure split-bf16 MFMA GEMM on K-slabbed planes.
// A: [6][M][32] hi/lo; W: [6][NC][32] hi/lo. Per 32-K slab, A(64x32) and
// B(192x32) tiles staged to LDS via global_load_lds w16 (linear dest,
// pre-swizzled source chunk c ^= (row>>1)&3; same XOR on ds_read addrs ->
// 2-way banks). Block 64M x 192N, 4 waves (2m x 2n), wave 32x96.
// F32OUT: scatter f32 (b2=m/49, row stride 192); else slabbed hi/lo out.
// NOTE: A stage may read up to 4KB past the plane tail (rows clamped only
// at epilogue) -- launcher leaves a 64KB pad at the end of workspace.
// ---------------------------------------------------------------------------
template<int NC, bool DUAL, bool F32OUT>
__global__ __launch_bounds__(256, 3) void gemm_m97(
    const ushort* __restrict__ Ah1, const ushort* __restrict__ Al1,
    const ushort* __restrict__ Ah2, const ushort* __restrict__ Al2,
    const ushort* __restrict__ Bh1, const ushort* __restrict__ Bl1,
    const ushort* __restrict__ Bh2, const ushort* __restrict__ Bl2,
    const float* __restrict__ bias,
    ushort* __restrict__ outH, ushort* __restrict__ outL,
    float* __restrict__ outF, long long out_bs,
    int M)
{
    __shared__ __align__(16) ushort AHs[2048];   // 64 x 32
    __shared__ __align__(16) ushort ALs[2048];
    __shared__ __align__(16) ushort BHs[6144];   // 192 x 32
    __shared__ __align__(16) ushort BLs[6144];

    const int tid = threadIdx.x;
    const int lane = tid & 63, wv = tid >> 6;
    const int wm = (wv >> 1) * 32;
    const int wn = (wv & 1) * 96;
    const int lr = lane & 15, lg = lane >> 4;
    const int bn = blockIdx.x, bm = blockIdx.y;
    const long long SS = (long long)M * 32;
    constexpr int NS = DUAL ? 12 : 6;

    // ---- staging source offsets (swizzled chunk) ----
    const int at_row = tid >> 2;
    const int at_c   = (tid & 3) ^ ((tid >> 3) & 3);
    const long long a_src = (long long)(bm * 64 + at_row) * 32 + at_c * 8;
    int b_src[3];
    #pragma unroll
    for (int k = 0; k < 3; ++k) {
        int t = k * 256 + tid;
        int row = t >> 2, c = (t & 3) ^ ((t >> 3) & 3);
        b_src[k] = (bn * 192 + row) * 32 + c * 8;
    }
    const int wdst = wv * 512;   // wave-uniform LDS base (ushorts)

    // ---- ds_read fragment offsets (swizzled) ----
    int aoff[2], boff[6];
    #pragma unroll
    for (int i = 0; i < 2; ++i) {
        int row = wm + 16 * i + lr;
        aoff[i] = (row * 4 + (lg ^ ((row >> 1) & 3))) * 8;
    }
    #pragma unroll
    for (int j = 0; j < 6; ++j) {
        int row = wn + 16 * j + lr;
        boff[j] = (row * 4 + (lg ^ ((row >> 1) & 3))) * 8;
    }

    f32x4 acc[2][6] = {};

    #pragma unroll
    for (int s = 0; s < NS; ++s) {
        const int k6 = (s < 6) ? s : s - 6;
        const ushort* AHp = (!DUAL || s < 6) ? Ah1 : Ah2;
        const ushort* ALp = (!DUAL || s < 6) ? Al1 : Al2;
        const ushort* BHp = (!DUAL || s < 6) ? Bh1 : Bh2;
        const ushort* BLp = (!DUAL || s < 6) ? Bl1 : Bl2;
        const long long asb = (long long)k6 * SS;
        const int bsb = k6 * (NC * 32);

        gld16(AHp + asb + a_src, AHs + wdst);
        gld16(ALp + asb + a_src, ALs + wdst);
        #pragma unroll
        for (int k = 0; k < 3; ++k) {
            gld16(BHp + bsb + b_src[k], BHs + k * 2048 + wdst);
            gld16(BLp + bsb + b_src[k], BLs + k * 2048 + wdst);
        }
        __syncthreads();   // drain vmcnt -> tile visible

        bf16x8 ah[2], al[2];
        #pragma unroll
        for (int i = 0; i < 2; ++i) {
            ah[i] = *(const bf16x8*)&AHs[aoff[i]];
            al[i] = *(const bf16x8*)&ALs[aoff[i]];
        }
        #pragma unroll
        for (int j = 0; j < 6; ++j) {
            bf16x8 bh = *(const bf16x8*)&BHs[boff[j]];
            bf16x8 bl = *(const bf16x8*)&BLs[boff[j]];
            #pragma unroll
            for (int i = 0; i < 2; ++i) {
                acc[i][j] = __builtin_amdgcn_mfma_f32_16x16x32_bf16(ah[i], bh, acc[i][j], 0, 0, 0);
                acc[i][j] = __builtin_amdgcn_mfma_f32_16x16x32_bf16(ah[i], bl, acc[i][j], 0, 0, 0);
                acc[i][j] = __builtin_amdgcn_mfma_f32_16x16x32_bf16(al[i], bh, acc[i][j], 0, 0, 0);
            }
        }
        __syncthreads();   // all reads done before next stage overwrites
    }

    // ---- epilogue ----
    #pragma unroll
    for (int j = 0; j < 6; ++j) {
        const int c = bn * 192 + wn + 16 * j + lr;
        const float bv = bias ? bias[c] : 0.f;
        #pragma unroll
        for (int i = 0; i < 2; ++i)
            #pragma unroll
            for (int r = 0; r < 4; ++r) {
                int m = bm * 64 + wm + 16 * i + 4 * lg + r;
                if (m < M) {
                    float f = acc[i][j][r] + bv;
                    if constexpr (F32OUT) {
                        int b2 = m / 49, r2 = m - b2 * 49;
                        outF[(long long)b2 * out_bs + r2 * 192 + c] = f;
                    } else {
                        long long o = (long long)(c >> 5) * SS + (long long)m * 32 + (c & 31);
                        ushort hh = bf16h(f);
                        outH[o] = hh;
                        outL[o] = bf16h(f - bf16f(hh));
                    }
                }
            }
    }
}

// ---------------------------------------------------------------------------
// MFMA differential attention on K-slabbed hi/lo planes (round-5 version).
// ---------------------------------------------------------------------------
__global__ __launch_bounds__(256, 4) void attn_bf(
    const ushort* __restrict__ qTh, const ushort* __restrict__ qTl,
    const ushort* __restrict__ kTh, const ushort* __restrict__ kTl,
    const ushort* __restrict__ vTh, const ushort* __restrict__ vTl,
    const ushort* __restrict__ qRh, const ushort* __restrict__ qRl,
    const ushort* __restrict__ kRh, const ushort* __restrict__ kRl,
    const ushort* __restrict__ vRh, const ushort* __restrict__ vRl,
    long long SS,
    const float* __restrict__ rpb, const float* __restrict__ lam_ptr,
    ushort* __restrict__ otH, ushort* __restrict__ otL,
    ushort* __restrict__ orH, ushort* __restrict__ orL)
{
    __shared__ __align__(16) ushort Pth[64][72];
    __shared__ __align__(16) ushort Ptl[64][72];
    __shared__ float bias_s[169];

    const int tid = threadIdx.x;
    const int bb = blockIdx.x / 6;
    const int h  = blockIdx.x - bb * 6;
    const int lane = tid & 63;
    const int w  = tid >> 6;
    const int li = lane & 15;
    const int lg = lane >> 4;
    const long long rowbase = (long long)bb * 49 * 32;
    const long long hb = (long long)h * SS + rowbase;

    for (int idx = tid; idx < 169; idx += 256) bias_s[idx] = rpb[idx * 6 + h];

    float lraw = lam_ptr[0];
    float lam = 1.f / (1.f + __expf(-lraw));
    lam = fminf(fmaxf(lam, 0.01f), 0.99f);

    const int irow = min(w * 16 + li, 48);

    f32x4 st[2][4];
    #pragma unroll
    for (int s = 0; s < 2; ++s) {
        const ushort* qhb = (s ? qRh : qTh) + hb;
        const ushort* qlb = (s ? qRl : qTl) + hb;
        const ushort* khb = (s ? kRh : kTh) + hb;
        const ushort* klb = (s ? kRl : kTl) + hb;

        bf16x8 qh = *(const bf16x8*)(qhb + irow * 32 + 8 * lg);
        bf16x8 ql = *(const bf16x8*)(qlb + irow * 32 + 8 * lg);
        #pragma unroll
        for (int jt = 0; jt < 4; ++jt) {
            int jr = jt * 16 + li; if (jr > 48) jr = 48;
            bf16x8 kh = *(const bf16x8*)(khb + jr * 32 + 8 * lg);
            bf16x8 kl = *(const bf16x8*)(klb + jr * 32 + 8 * lg);
            f32x4 c = {};
            c = __builtin_amdgcn_mfma_f32_16x16x32_bf16(kh, qh, c, 0, 0, 0);
            c = __builtin_amdgcn_mfma_f32_16x16x32_bf16(kh, ql, c, 0, 0, 0);
            c = __builtin_amdgcn_mfma_f32_16x16x32_bf16(kl, qh, c, 0, 0, 0);
            st[s][jt] = c;
        }
    }
    __syncthreads();   // bias_s ready (only barrier)

    const int ri = (irow * 9363) >> 16;
    const int ci = irow - 7 * ri;
    float bias_v[4][4];
    #pragma unroll
    for (int jt = 0; jt < 4; ++jt)
        #pragma unroll
        for (int r = 0; r < 4; ++r) {
            int j = jt * 16 + 4 * lg + r;
            int jc = (j < 49) ? j : 48;
            int rj = (jc * 9363) >> 16;
            int cj = jc - 7 * rj;
            bias_v[jt][r] = bias_s[(ri - rj + 6) * 13 + (ci - cj + 6)];
        }

    float p[2][4][4];
    #pragma unroll
    for (int s = 0; s < 2; ++s) {
        float m = -1e30f;
        #pragma unroll
        for (int jt = 0; jt < 4; ++jt)
            #pragma unroll
            for (int r = 0; r < 4; ++r) {
                int j = jt * 16 + 4 * lg + r;
                float sv = (j < 49) ? (st[s][jt][r] * SCALE_ + bias_v[jt][r]) : -1e30f;
                p[s][jt][r] = sv;
                m = fmaxf(m, sv);
            }
        m = fmaxf(m, __shfl_xor(m, 16));
        m = fmaxf(m, __shfl_xor(m, 32));
        float sum = 0.f;
        #pragma unroll
        for (int jt = 0; jt < 4; ++jt)
            #pragma unroll
            for (int r = 0; r < 4; ++r) {
                float e = __expf(p[s][jt][r] - m);
                p[s][jt][r] = e;
                sum += e;
            }
        sum += __shfl_xor(sum, 16);
        sum += __shfl_xor(sum, 32);
        float inv = 1.f / sum;
        #pragma unroll
        for (int jt = 0; jt < 4; ++jt)
            #pragma unroll
            for (int r = 0; r < 4; ++r)
                p[s][jt][r] *= inv;
    }

    const int prow = w * 16 + li;
    #pragma unroll
    for (int s = 0; s < 2; ++s) {
        #pragma unroll
        for (int jt = 0; jt < 4; ++jt) {
            ushort4 h4, l4;
            #pragma unroll
            for (int r = 0; r < 4; ++r) {
                float at = p[0][jt][r], ar = p[1][jt][r];
                float f = (s == 0) ? (at - lam * ar) : (ar - lam * at);
                ushort hh = bf16h(f);
                ((ushort*)&h4)[r] = hh;
                ((ushort*)&l4)[r] = bf16h(f - bf16f(hh));
            }
            *(ushort4*)&Pth[prow][jt * 16 + 4 * lg] = h4;
            *(ushort4*)&Ptl[prow][jt * 16 + 4 * lg] = l4;
        }

        const ushort* vhb = (s ? vRh : vTh) + hb;
        const ushort* vlb = (s ? vRl : vTl) + hb;
        f32x4 acc[2] = {};
        #pragma unroll
        for (int ks = 0; ks < 2; ++ks) {
            bf16x8 pah = *(const bf16x8*)&Pth[prow][ks * 32 + 8 * lg];
            bf16x8 pal = *(const bf16x8*)&Ptl[prow][ks * 32 + 8 * lg];
            #pragma unroll
            for (int dt = 0; dt < 2; ++dt) {
                bf16x8 vh, vl;
                #pragma unroll
                for (int e = 0; e < 8; ++e) {
                    long long o = (long long)(ks * 32 + 8 * lg + e) * 32 + dt * 16 + li;
                    vh[e] = (short)vhb[o];
                    vl[e] = (short)vlb[o];
                }
                acc[dt] = __builtin_amdgcn_mfma_f32_16x16x32_bf16(pah, vh, acc[dt], 0, 0, 0);
                acc[dt] = __builtin_amdgcn_mfma_f32_16x16x32_bf16(pah, vl, acc[dt], 0, 0, 0);
                acc[dt] = __builtin_amdgcn_mfma_f32_16x16x32_bf16(pal, vh, acc[dt], 0, 0, 0);
            }
        }
        ushort* oph = s ? orH : otH;
        ushort* opl = s ? orL : otL;
        #pragma unroll
        for (int dt = 0; dt < 2; ++dt)
            #pragma unroll
            for (int r = 0; r < 4; ++r) {
                int i = w * 16 + 4 * lg + r;
                if (i < 49) {
                    long long o = (long long)h * SS + rowbase + (long long)i * 32 + dt * 16 + li;
                    float f = acc[dt][r];
                    ushort hh = bf16h(f);
                    oph[o] = hh;
                    opl[o] = bf16h(f - bf16f(hh));
                }
            }
    }
}

// ---------------------------------------------------------------------------
extern "C" void kernel_launch(void* const* d_in, const int* in_sizes, int n_in,
                              void* d_out, int out_size, void* d_ws, size_t ws_size,
                              hipStream_t stream)
{
    const float* x_sa      = (const float*)d_in[0];
    const float* x_ca      = (const float*)d_in[1];
    const float* lam_sa    = (const float*)d_in[2];
    const float* lam_ca    = (const float*)d_in[3];
    const float* sa_enh    = (const float*)d_in[4];
    const float* ca_enh    = (const float*)d_in[5];
    const float* W_sa_qkv  = (const float*)d_in[6];
    const float* b_sa_qkv  = (const float*)d_in[7];
    const float* W_sa_ct   = (const float*)d_in[8];
    const float* W_sa_cr   = (const float*)d_in[9];
    const float* W_ca_q    = (const float*)d_in[10];
    const float* b_ca_q    = (const float*)d_in[11];
    const float* W_ca_kv   = (const float*)d_in[12];
    const float* b_ca_kv   = (const float*)d_in[13];
    const float* W_ca_ct   = (const float*)d_in[14];
    const float* W_ca_cr   = (const float*)d_in[15];
    const float* rpb       = (const float*)d_in[16];
    const float* W_proj_sa = (const float*)d_in[17];
    const float* b_proj_sa = (const float*)d_in[18];
    const float* W_proj_ca = (const float*)d_in[19];
    const float* b_proj_ca = (const float*)d_in[20];
    float* out = (float*)d_out;
    float* ws  = (float*)d_ws;

    // ---- f32 combined-weight temps ----
    float* CW0 = ws;             // 192x576
    float* CW1 = CW0 + 110592;
    float* CW2 = CW1 + 110592;   // 192x192
    float* CW3 = CW2 + 36864;
    float* CW4 = CW3 + 36864;    // 192x384
    float* CW5 = CW4 + 73728;

    smallmm_kernel<<<108, 256, 0, stream>>>(W_sa_cr, W_sa_qkv, sa_enh, CW0, 576);
    smallmm_kernel<<<108, 256, 0, stream>>>(W_sa_ct, W_sa_qkv, sa_enh, CW1, 576);
    smallmm_kernel<<< 36, 256, 0, stream>>>(W_ca_cr, W_ca_q,   ca_enh, CW2, 192);
    smallmm_kernel<<< 36, 256, 0, stream>>>(W_ca_ct, W_ca_q,   ca_enh, CW3, 192);
    smallmm_kernel<<< 72, 256, 0, stream>>>(W_ca_cr, W_ca_kv,  ca_enh, CW4, 384);
    smallmm_kernel<<< 72, 256, 0, stream>>>(W_ca_ct, W_ca_kv,  ca_enh, CW5, 384);

    // ---- K-slabbed bf16 hi/lo weights ----
    ushort* wb = (ushort*)(ws + 442368);
    ushort* WsaqH = wb;                  ushort* WsaqL = WsaqH + 110592;
    ushort* C0H  = WsaqL + 110592;       ushort* C0L  = C0H + 110592;
    ushort* C1H  = C0L + 110592;         ushort* C1L  = C1H + 110592;
    ushort* WcqH = C1L + 110592;         ushort* WcqL = WcqH + 36864;
    ushort* C2H  = WcqL + 36864;         ushort* C2L  = C2H + 36864;
    ushort* C3H  = C2L + 36864;          ushort* C3L  = C3H + 36864;
    ushort* WckH = C3L + 36864;          ushort* WckL = WckH + 73728;
    ushort* C4H  = WckL + 73728;         ushort* C4L  = C4H + 73728;
    ushort* C5H  = C4L + 73728;          ushort* C5L  = C5H + 73728;
    ushort* WpsH = C5L + 73728;          ushort* WpsL = WpsH + 36864;
    ushort* WpcH = WpsL + 36864;         ushort* WpcL = WpcH + 36864;
    ushort* chunkU = WpcL + 36864;       // = wb + 1474560

    conv_wT<<<432, 256, 0, stream>>>(W_sa_qkv, 576, WsaqH, WsaqL);
    conv_wT<<<432, 256, 0, stream>>>(CW0,      576, C0H,  C0L);
    conv_wT<<<432, 256, 0, stream>>>(CW1,      576, C1H,  C1L);
    conv_wT<<<144, 256, 0, stream>>>(W_ca_q,   192, WcqH, WcqL);
    conv_wT<<<144, 256, 0, stream>>>(CW2,      192, C2H,  C2L);
    conv_wT<<<144, 256, 0, stream>>>(CW3,      192, C3H,  C3L);
    conv_wT<<<288, 256, 0, stream>>>(W_ca_kv,  384, WckH, WckL);
    conv_wT<<<288, 256, 0, stream>>>(CW4,      384, C4H,  C4L);
    conv_wT<<<288, 256, 0, stream>>>(CW5,      384, C5H,  C5L);
    conv_wT<<<144, 256, 0, stream>>>(W_proj_sa,192, WpsH, WpsL);
    conv_wT<<<144, 256, 0, stream>>>(W_proj_ca,192, WpcH, WpcL);

    // ---- chunking: 376320 bytes per batch element, 64KB tail pad ----
    long long avail = (long long)ws_size - 442368LL * 4 - 1474560LL * 2 - 65536;
    int cbmax = (int)(avail / 376320);
    if (cbmax > 2048) cbmax = 2048;
    if (cbmax < 1) cbmax = 1;

    const long long OUT1 = 2LL * 2048 * 49 * 192;
    dim3 blk(256);

    for (int c0 = 0; c0 < 2048; c0 += cbmax) {
        int cb = (c0 + cbmax <= 2048) ? cbmax : (2048 - c0);
        int M = cb * 49;
        long long SS = (long long)M * 32;
        int gy = (M + 63) / 64;
        int cblk = (int)(((long long)M * 24 + 255) / 256);
        if (cblk > 4096) cblk = 4096;

        dim3 g1(3, gy), g2(1, gy), g3(2, gy);

        // =========================== SA branch ===========================
        ushort* XtH = chunkU;                              // [6][M][32] each
        ushort* XtL = XtH + (long long)cbmax * 9408;
        ushort* XrH = XtL + (long long)cbmax * 9408;
        ushort* XrL = XrH + (long long)cbmax * 9408;
        ushort* QtH = XrL + (long long)cbmax * 9408;       // [18][M][32]
        ushort* QtL = QtH + (long long)cbmax * 28224;
        ushort* QrH = QtL + (long long)cbmax * 28224;
        ushort* QrL = QrH + (long long)cbmax * 28224;
        ushort* OtH = QrL + (long long)cbmax * 28224;      // [6][M][32]
        ushort* OtL = OtH + (long long)cbmax * 9408;
        ushort* OrH = OtL + (long long)cbmax * 9408;
        ushort* OrL = OrH + (long long)cbmax * 9408;

        conv_x<<<cblk, blk, 0, stream>>>(x_sa + (long long)c0 * 9408, 9408, XtH, XtL, M);
        conv_x<<<cblk, blk, 0, stream>>>(x_sa + (2048LL + c0) * 9408, 9408, XrH, XrL, M);

        gemm_m97<576, true, false><<<g1, blk, 0, stream>>>(
            XtH, XtL, XrH, XrL, WsaqH, WsaqL, C0H, C0L,
            b_sa_qkv, QtH, QtL, nullptr, 0, M);
        gemm_m97<576, true, false><<<g1, blk, 0, stream>>>(
            XrH, XrL, XtH, XtL, WsaqH, WsaqL, C1H, C1L,
            b_sa_qkv, QrH, QrL, nullptr, 0, M);

        attn_bf<<<cb * 6, blk, 0, stream>>>(
            QtH,           QtL,
            QtH + 6 * SS,  QtL + 6 * SS,
            QtH + 12 * SS, QtL + 12 * SS,
            QrH,           QrL,
            QrH + 6 * SS,  QrL + 6 * SS,
            QrH + 12 * SS, QrL + 12 * SS,
            SS, rpb, lam_sa, OtH, OtL, OrH, OrL);

        gemm_m97<192, false, true><<<g2, blk, 0, stream>>>(
            OtH, OtL, nullptr, nullptr, WpsH, WpsL, nullptr, nullptr,
            b_proj_sa, nullptr, nullptr, out + (long long)c0 * 9408, 9408, M);
        gemm_m97<192, false, true><<<g2, blk, 0, stream>>>(
            OrH, OrL, nullptr, nullptr, WpsH, WpsL, nullptr, nullptr,
            b_proj_sa, nullptr, nullptr, out + (2048LL + c0) * 9408, 9408, M);

        // =========================== CA branch ===========================
        ushort* CXtH = chunkU;                             // [6][M][32]
        ushort* CXtL = CXtH + (long long)cbmax * 9408;
        ushort* CXrH = CXtL + (long long)cbmax * 9408;
        ushort* CXrL = CXrH + (long long)cbmax * 9408;
        ushort* CQtH = CXrL + (long long)cbmax * 9408;     // [6][M][32]
        ushort* CQtL = CQtH + (long long)cbmax * 9408;
        ushort* CQrH = CQtL + (long long)cbmax * 9408;
        ushort* CQrL = CQrH + (long long)cbmax * 9408;
        ushort* KtH  = CQrL + (long long)cbmax * 9408;     // [12][M][32]
        ushort* KtL  = KtH + (long long)cbmax * 18816;
        ushort* KrH  = KtL + (long long)cbmax * 18816;
        ushort* KrL  = KrH + (long long)cbmax * 18816;
        ushort* COtH = KrL + (long long)cbmax * 18816;     // [6][M][32]
        ushort* COtL = COtH + (long long)cbmax * 9408;
        ushort* COrH = COtL + (long long)cbmax * 9408;
        ushort* COrL = COrH + (long long)cbmax * 9408;

        conv_x<<<cblk, blk, 0, stream>>>(x_ca + (long long)c0 * 18816, 18816, CXtH, CXtL, M);
        conv_x<<<cblk, blk, 0, stream>>>(x_ca + (long long)c0 * 18816 + 9408, 18816, CXrH, CXrL, M);

        gemm_m97<192, true, false><<<g2, blk, 0, stream>>>(
            CXtH, CXtL, CXrH, CXrL, WcqH, WcqL, C2H, C2L,
            b_ca_q, CQtH, CQtL, nullptr, 0, M);
        gemm_m97<192, true, false><<<g2, blk, 0, stream>>>(
            CXrH, CXrL, CXtH, CXtL, WcqH, WcqL, C3H, C3L,
            b_ca_q, CQrH, CQrL, nullptr, 0, M);

        gemm_m97<384, true, false><<<g3, blk, 0, stream>>>(
            CXtH, CXtL, CXrH, CXrL, WckH, WckL, C4H, C4L,
            b_ca_kv, KtH, KtL, nullptr, 0, M);
        gemm_m97<384, true, false><<<g3, blk, 0, stream>>>(
            CXrH, CXrL, CXtH, CXtL, WckH, WckL, C5H, C5L,
            b_ca_kv, KrH, KrL, nullptr, 0, M);

        attn_bf<<<cb * 6, blk, 0, stream>>>(
            CQtH,         CQtL,
            KtH,          KtL,
            KtH + 6 * SS, KtL + 6 * SS,
            CQrH,         CQrL,
            KrH,          KrL,
            KrH + 6 * SS, KrL + 6 * SS,
            SS, rpb, lam_ca, COtH, COtL, COrH, COrL);

        gemm_m97<192, false, true><<<g2, blk, 0, stream>>>(
            COtH, COtL, nullptr, nullptr, WpcH, WpcL, nullptr, nullptr,
            b_proj_ca, nullptr, nullptr,
            out + OUT1 + (long long)c0 * 18816, 18816, M);
        gemm_m97<192, false, true><<<g2, blk, 0, stream>>>(
            COrH, COrL, nullptr, nullptr, WpcH, WpcL, nullptr, nullptr,
            b_proj_ca, nullptr, nullptr,
            out + OUT1 + (long long)c0 * 18816 + 9408, 18816, M);
    }
}